// Round 4
// baseline (224.665 us; speedup 1.0000x reference)
//
#include <hip/hip_runtime.h>
#include <hip/hip_cooperative_groups.h>

namespace cg = cooperative_groups;

constexpr int cB = 8, cN = 4096, cD = 1024, cH = 1792;

// Workspace offsets (floats). Every word is written before read -> no memset.
constexpr size_t OFF_PART   = 0;                        // [256][1024] per-block xsum partials
constexpr size_t OFF_VPART  = OFF_PART  + 256 * 1024;   // [256][8192] per-block v partials
constexpr size_t OFF_VPART2 = OFF_VPART + (size_t)256 * 8192;  // [8][8192]
constexpr size_t OFF_XSUM   = OFF_VPART2 + 8 * 8192;    // [8][1024]
constexpr size_t OFF_KSUM   = OFF_XSUM + 8 * 1024;      // [8][1792]
constexpr size_t OFF_V      = OFF_KSUM + 8 * 1792;      // [8][1024]
constexpr size_t OFF_C      = OFF_V + 8 * 1024;         // [8] (pad 64)
constexpr size_t WS_FLOATS  = OFF_C + 64;               // ~2.42M floats ~ 9.7 MB

__device__ __forceinline__ float dot4(float4 a, float4 b) {
    return a.x * b.x + a.y * b.y + a.z * b.z + a.w * b.w;
}

// ---------------------------------------------------------------------------
// Phase A: part[g][d] = sum of 128 consecutive rows of x (g = b*32+ns).
// 4 row-groups per block, LDS-reduced so each block emits ONE partial.
__device__ __forceinline__ void phaseA(const float* __restrict__ x,
                                       float* __restrict__ part,
                                       int g, int t, float4* lds) {
    int b = g >> 5, ns = g & 31;
    int rg = t >> 8, col = t & 255;
    const float4* xp = (const float4*)(x + ((size_t)b * cN + ns * 128 + rg) * cD) + col;
    float4 acc = make_float4(0.f, 0.f, 0.f, 0.f);
#pragma unroll 8
    for (int k = 0; k < 32; ++k) {           // rows rg, rg+4, ..., rg+124
        float4 v2 = xp[(size_t)k * 4 * (cD / 4)];
        acc.x += v2.x; acc.y += v2.y; acc.z += v2.z; acc.w += v2.w;
    }
    lds[rg * 256 + col] = acc;
    __syncthreads();
    if (rg == 0) {
        float4 a0 = lds[col], a1 = lds[256 + col], a2 = lds[512 + col], a3 = lds[768 + col];
        float4 s;
        s.x = (a0.x + a1.x) + (a2.x + a3.x);
        s.y = (a0.y + a1.y) + (a2.y + a3.y);
        s.z = (a0.z + a1.z) + (a2.z + a3.z);
        s.w = (a0.w + a1.w) + (a2.w + a3.w);
        ((float4*)(part + (size_t)g * cD))[col] = s;
    }
}

// Phase B: xsum[b][d] = sum_ns part[b*32+ns][d].  Blocks 0..7 (b = g).
__device__ __forceinline__ void phaseB(const float* __restrict__ part,
                                       float* __restrict__ xsum, int g, int t) {
    if (g >= cB) return;
    const float* p = part + (size_t)g * 32 * cD + t;
    float acc = 0.f;
#pragma unroll
    for (int ns = 0; ns < 32; ++ns) acc += p[(size_t)ns * cD];
    xsum[(size_t)g * cD + t] = acc;
}

// Phase C: per block g: 7 h-values; wave w = batch b (waves 8..15 idle).
//   ksum[b,h] = xsum[b]·Wk[h] + N*bk[h]   (wave shuffle-reduce, broadcast)
//   vpart[g][b][d] = sum_h Wq[h][d]*ksum
__device__ __forceinline__ void phaseC(const float* __restrict__ xsum,
                                       const float* __restrict__ Wk,
                                       const float* __restrict__ bk,
                                       const float* __restrict__ Wq,
                                       const float* __restrict__ bq,
                                       float* __restrict__ vpart,
                                       float* __restrict__ ksum, int g, int t) {
    int w = t >> 6, l = t & 63;
    if (w >= cB) return;
    int b = w;
    const float4* xs4 = (const float4*)(xsum + (size_t)b * cD);
    float4 xr[4];
#pragma unroll
    for (int j = 0; j < 4; ++j) xr[j] = xs4[l + 64 * j];
    float4 vacc[4];
#pragma unroll
    for (int j = 0; j < 4; ++j) vacc[j] = make_float4(0.f, 0.f, 0.f, 0.f);
    int h0 = g * 7;
    for (int i = 0; i < 7; ++i) {
        int h = h0 + i;
        const float4* wk4 = (const float4*)(Wk + (size_t)h * cD);
        float pd = 0.f;
#pragma unroll
        for (int j = 0; j < 4; ++j) pd += dot4(wk4[l + 64 * j], xr[j]);
#pragma unroll
        for (int off = 32; off; off >>= 1) pd += __shfl_xor(pd, off);
        float ks = pd + (float)cN * bk[h];
        if (l == 0) ksum[(size_t)b * cH + h] = ks;
        const float4* wq4 = (const float4*)(Wq + (size_t)h * cD);
#pragma unroll
        for (int j = 0; j < 4; ++j) {
            float4 q = wq4[l + 64 * j];
            vacc[j].x = fmaf(q.x, ks, vacc[j].x);
            vacc[j].y = fmaf(q.y, ks, vacc[j].y);
            vacc[j].z = fmaf(q.z, ks, vacc[j].z);
            vacc[j].w = fmaf(q.w, ks, vacc[j].w);
        }
    }
    float4* vp = (float4*)(vpart + (size_t)g * (cB * cD) + (size_t)b * cD);
#pragma unroll
    for (int j = 0; j < 4; ++j) vp[l + 64 * j] = vacc[j];
}

// Phase D0: vpart2[q][bd] = sum_{k<32} vpart[q*32+k][bd].  Blocks 0..63.
__device__ __forceinline__ void phaseD0(const float* __restrict__ vpart,
                                        float* __restrict__ vpart2, int g, int t) {
    if (g >= 64) return;
    int q = g >> 3;
    size_t bd = (size_t)(g & 7) * 1024 + t;
    const float* p = vpart + (size_t)q * 32 * 8192 + bd;
    float acc = 0.f;
#pragma unroll
    for (int k = 0; k < 32; ++k) acc += p[(size_t)k * 8192];
    vpart2[(size_t)q * 8192 + bd] = acc;
}

// Phase D1: v[bd] = sum_q vpart2[q][bd] (blocks 0..7); block 8: c[b] = bq·ksum[b].
__device__ __forceinline__ void phaseD1(const float* __restrict__ vpart2,
                                        const float* __restrict__ ksum,
                                        const float* __restrict__ bq,
                                        float* __restrict__ v,
                                        float* __restrict__ cvec, int g, int t) {
    if (g < cB) {
        size_t bd = (size_t)g * 1024 + t;
        float acc = 0.f;
#pragma unroll
        for (int q = 0; q < 8; ++q) acc += vpart2[(size_t)q * 8192 + bd];
        v[bd] = acc;
    } else if (g == cB) {
        int w = t >> 6, l = t & 63;
        if (w < cB) {
            float acc = 0.f;
#pragma unroll 7
            for (int h = l; h < cH; h += 64) acc += bq[h] * ksum[(size_t)w * cH + h];
#pragma unroll
            for (int off = 32; off; off >>= 1) acc += __shfl_xor(acc, off);
            if (l == 0) cvec[w] = acc;
        }
    }
}

// Phase E: scores[row] = (x[row]·v[b] + c[b]) * (1/(N*sqrt(H))).  128 rows/block.
__device__ __forceinline__ void phaseE(const float* __restrict__ x,
                                       const float* __restrict__ v,
                                       const float* __restrict__ cvec,
                                       float* __restrict__ out,
                                       int g, int t, float4* lds) {
    int row0 = g * 128;
    int b = g >> 5;
    if (t < 256) lds[t] = ((const float4*)(v + (size_t)b * cD))[t];
    __syncthreads();
    int w = t >> 6, l = t & 63;
    float4 vv[4];
#pragma unroll
    for (int j = 0; j < 4; ++j) vv[j] = lds[l + 64 * j];
    float cb = cvec[b];
    const float scale = (1.0f / 4096.0f) * (1.0f / sqrtf(1792.0f));
    int row = row0 + w * 8;
#pragma unroll
    for (int rp = 0; rp < 4; ++rp) {   // 4 pairs of interleaved rows
        const float4* xa = (const float4*)(x + (size_t)(row + 2 * rp) * cD);
        const float4* xb = (const float4*)(x + (size_t)(row + 2 * rp + 1) * cD);
        float a0 = 0.f, a1 = 0.f;
#pragma unroll
        for (int j = 0; j < 4; ++j) {
            a0 += dot4(xa[l + 64 * j], vv[j]);
            a1 += dot4(xb[l + 64 * j], vv[j]);
        }
#pragma unroll
        for (int off = 32; off; off >>= 1) {
            a0 += __shfl_xor(a0, off);
            a1 += __shfl_xor(a1, off);
        }
        if (l == 0) {
            out[row + 2 * rp]     = (a0 + cb) * scale;
            out[row + 2 * rp + 1] = (a1 + cb) * scale;
        }
    }
}

// ---------------------------------------------------------------------------
// Cooperative mega-kernel: all phases, grid.sync() between them.
__global__ __launch_bounds__(1024, 4) void mega(const float* __restrict__ x,
                                                const float* __restrict__ Wq,
                                                const float* __restrict__ bq,
                                                const float* __restrict__ Wk,
                                                const float* __restrict__ bk,
                                                float* __restrict__ out,
                                                float* __restrict__ ws) {
    __shared__ float4 lds[1024];
    cg::grid_group grid = cg::this_grid();
    int g = blockIdx.x, t = threadIdx.x;
    float* part   = ws + OFF_PART;
    float* vpart  = ws + OFF_VPART;
    float* vpart2 = ws + OFF_VPART2;
    float* xsum   = ws + OFF_XSUM;
    float* ksum   = ws + OFF_KSUM;
    float* v      = ws + OFF_V;
    float* cvec   = ws + OFF_C;

    phaseA(x, part, g, t, lds);
    grid.sync();
    phaseB(part, xsum, g, t);
    grid.sync();
    phaseC(xsum, Wk, bk, Wq, bq, vpart, ksum, g, t);
    grid.sync();
    phaseD0(vpart, vpart2, g, t);
    grid.sync();
    phaseD1(vpart2, ksum, bq, v, cvec, g, t);
    grid.sync();
    phaseE(x, v, cvec, out, g, t, lds);
}

// ---------------------------------------------------------------------------
// Fallback: identical phases as plain kernels (if cooperative launch errors).
__global__ __launch_bounds__(1024, 4) void FA(const float* __restrict__ x, float* ws) {
    __shared__ float4 lds[1024];
    phaseA(x, ws + OFF_PART, blockIdx.x, threadIdx.x, lds);
}
__global__ __launch_bounds__(1024) void FB(float* ws) {
    phaseB(ws + OFF_PART, ws + OFF_XSUM, blockIdx.x, threadIdx.x);
}
__global__ __launch_bounds__(1024) void FC(const float* Wk, const float* bk,
                                           const float* Wq, const float* bq, float* ws) {
    phaseC(ws + OFF_XSUM, Wk, bk, Wq, bq, ws + OFF_VPART, ws + OFF_KSUM,
           blockIdx.x, threadIdx.x);
}
__global__ __launch_bounds__(1024) void FD0(float* ws) {
    phaseD0(ws + OFF_VPART, ws + OFF_VPART2, blockIdx.x, threadIdx.x);
}
__global__ __launch_bounds__(1024) void FD1(const float* bq, float* ws) {
    phaseD1(ws + OFF_VPART2, ws + OFF_KSUM, bq, ws + OFF_V, ws + OFF_C,
            blockIdx.x, threadIdx.x);
}
__global__ __launch_bounds__(1024) void FE(const float* __restrict__ x, float* ws,
                                           float* __restrict__ out) {
    __shared__ float4 lds[256];
    phaseE(x, ws + OFF_V, ws + OFF_C, out, blockIdx.x, threadIdx.x, lds);
}

// ---------------------------------------------------------------------------
extern "C" void kernel_launch(void* const* d_in, const int* in_sizes, int n_in,
                              void* d_out, int out_size, void* d_ws, size_t ws_size,
                              hipStream_t stream) {
    const float* x  = (const float*)d_in[0];
    const float* Wq = (const float*)d_in[1];
    const float* bq = (const float*)d_in[2];
    const float* Wk = (const float*)d_in[3];
    const float* bk = (const float*)d_in[4];
    float* out = (float*)d_out;
    float* ws  = (float*)d_ws;

    void* args[] = { (void*)&x, (void*)&Wq, (void*)&bq, (void*)&Wk, (void*)&bk,
                     (void*)&out, (void*)&ws };
    hipError_t err = hipLaunchCooperativeKernel((const void*)mega, dim3(256), dim3(1024),
                                                args, 0, stream);
    if (err != hipSuccess) {
        (void)hipGetLastError();
        FA <<<256,     1024, 0, stream>>>(x, ws);
        FB <<<cB,      1024, 0, stream>>>(ws);
        FC <<<256,     1024, 0, stream>>>(Wk, bk, Wq, bq, ws);
        FD0<<<64,      1024, 0, stream>>>(ws);
        FD1<<<cB + 1,  1024, 0, stream>>>(bq, ws);
        FE <<<256,     1024, 0, stream>>>(x, ws, out);
    }
}

// Round 5
// 113.585 us; speedup vs baseline: 1.9779x; 1.9779x over previous
//
#include <hip/hip_runtime.h>

// Problem constants (match reference)
constexpr int cB = 8;
constexpr int cN = 4096;
constexpr int cD = 1024;   // IN_FEATURES
constexpr int cH = 1792;   // HIDDEN_DIM

constexpr int NSPLIT = 128;  // k1 partial split over N (rows per block = 32)
constexpr int CH     = 16;   // k23: h-values per block
constexpr int HS     = cH / CH;  // 112 blocks

// Workspace layout (in floats)
constexpr size_t OFF_XSUM  = 0;                                   // 8192
constexpr size_t OFF_V     = OFF_XSUM + (size_t)cB * cD;          // 8192
constexpr size_t OFF_C     = OFF_V + (size_t)cB * cD;             // 8 (pad 64)
constexpr size_t OFF_CPART = OFF_C + 64;                          // HS*B = 896 (pad 1024)
constexpr size_t OFF_VPART = OFF_CPART + 1024;                    // HS*B*D = 917504
constexpr size_t OFF_PART  = OFF_VPART + (size_t)HS * cB * cD;    // B*NSPLIT*D = 1048576
constexpr size_t TOTAL_DET_FLOATS = OFF_PART + (size_t)cB * NSPLIT * cD;
constexpr size_t SMALL_FLOATS     = OFF_CPART;  // atomic-fallback accumulator region

__device__ __forceinline__ float dot4(float4 a, float4 b) {
    return a.x * b.x + a.y * b.y + a.z * b.z + a.w * b.w;
}

// ---------------------------------------------------------------------------
// k1a: part[b*NSPLIT+ns][d] = sum over 32 consecutive rows of x[b]
__global__ __launch_bounds__(256) void k1a_partial(const float* __restrict__ x,
                                                   float* __restrict__ part) {
    int bid = blockIdx.x;                 // 0 .. B*NSPLIT-1
    int b = bid / NSPLIT, ns = bid % NSPLIT;
    const int rows = cN / NSPLIT;         // 32
    const float4* xp = (const float4*)(x + ((size_t)b * cN + (size_t)ns * rows) * cD);
    int t = threadIdx.x;                  // one float4 column of the row
    float4 acc = make_float4(0.f, 0.f, 0.f, 0.f);
    for (int r = 0; r < rows; ++r) {
        float4 v = xp[(size_t)r * (cD / 4) + t];
        acc.x += v.x; acc.y += v.y; acc.z += v.z; acc.w += v.w;
    }
    ((float4*)part)[(size_t)bid * (cD / 4) + t] = acc;
}

// k1b: xsum[b][d] = sum_ns part[b*NSPLIT+ns][d]
__global__ __launch_bounds__(256) void k1b_reduce(const float* __restrict__ part,
                                                  float* __restrict__ xsum) {
    int idx = blockIdx.x * blockDim.x + threadIdx.x;  // b*cD + d, total 8192
    int b = idx / cD, d = idx % cD;
    float acc = 0.f;
    const float* p = part + (size_t)b * NSPLIT * cD + d;
    for (int ns = 0; ns < NSPLIT; ++ns) acc += p[(size_t)ns * cD];
    xsum[idx] = acc;
}

// k1 fallback: atomic accumulate directly into xsum (pre-zeroed)
__global__ __launch_bounds__(256) void k1_atomic(const float* __restrict__ x,
                                                 float* __restrict__ xsum) {
    int bid = blockIdx.x;
    int b = bid / NSPLIT, ns = bid % NSPLIT;
    const int rows = cN / NSPLIT;
    const float4* xp = (const float4*)(x + ((size_t)b * cN + (size_t)ns * rows) * cD);
    int t = threadIdx.x;
    float4 acc = make_float4(0.f, 0.f, 0.f, 0.f);
    for (int r = 0; r < rows; ++r) {
        float4 v = xp[(size_t)r * (cD / 4) + t];
        acc.x += v.x; acc.y += v.y; acc.z += v.z; acc.w += v.w;
    }
    float* dst = xsum + (size_t)b * cD + t * 4;
    atomicAdd(dst + 0, acc.x);
    atomicAdd(dst + 1, acc.y);
    atomicAdd(dst + 2, acc.z);
    atomicAdd(dst + 3, acc.w);
}

// ---------------------------------------------------------------------------
// k23: fused ksum -> (vpart, cpart).  Grid = HS blocks x 512 threads.
__global__ __launch_bounds__(512) void k23_fused(const float* __restrict__ xsum,
                                                 const float* __restrict__ Wk,
                                                 const float* __restrict__ bk,
                                                 const float* __restrict__ Wq,
                                                 const float* __restrict__ bq,
                                                 float* __restrict__ vpart,
                                                 float* __restrict__ cpart) {
    int w = threadIdx.x >> 6, l = threadIdx.x & 63;
    int b = w;                       // 8 waves == 8 batches
    int h0 = blockIdx.x * CH;

    const float4* xs4 = (const float4*)(xsum + (size_t)b * cD);
    float4 xr[4];
#pragma unroll
    for (int j = 0; j < 4; ++j) xr[j] = xs4[l + 64 * j];

    float4 vacc[4];
#pragma unroll
    for (int j = 0; j < 4; ++j) vacc[j] = make_float4(0.f, 0.f, 0.f, 0.f);
    float cacc = 0.f;

    for (int i = 0; i < CH; i += 2) {
        int ha = h0 + i, hb = h0 + i + 1;
        const float4* wka = (const float4*)(Wk + (size_t)ha * cD);
        const float4* wkb = (const float4*)(Wk + (size_t)hb * cD);
        float pa = 0.f, pb = 0.f;
#pragma unroll
        for (int j = 0; j < 4; ++j) {
            pa += dot4(wka[l + 64 * j], xr[j]);
            pb += dot4(wkb[l + 64 * j], xr[j]);
        }
#pragma unroll
        for (int off = 32; off; off >>= 1) {
            pa += __shfl_xor(pa, off);
            pb += __shfl_xor(pb, off);
        }
        float ksa = pa + (float)cN * bk[ha];
        float ksb = pb + (float)cN * bk[hb];
        cacc += bq[ha] * ksa + bq[hb] * ksb;
        const float4* wqa = (const float4*)(Wq + (size_t)ha * cD);
        const float4* wqb = (const float4*)(Wq + (size_t)hb * cD);
#pragma unroll
        for (int j = 0; j < 4; ++j) {
            float4 qa = wqa[l + 64 * j];
            float4 qb = wqb[l + 64 * j];
            vacc[j].x = fmaf(qa.x, ksa, fmaf(qb.x, ksb, vacc[j].x));
            vacc[j].y = fmaf(qa.y, ksa, fmaf(qb.y, ksb, vacc[j].y));
            vacc[j].z = fmaf(qa.z, ksa, fmaf(qb.z, ksb, vacc[j].z));
            vacc[j].w = fmaf(qa.w, ksa, fmaf(qb.w, ksb, vacc[j].w));
        }
    }

    float4* vp = (float4*)(vpart + ((size_t)blockIdx.x * cB + b) * cD);
#pragma unroll
    for (int j = 0; j < 4; ++j) vp[l + 64 * j] = vacc[j];
    if (l == 0) cpart[blockIdx.x * cB + b] = cacc;
}

// k23 fallback: atomics into v, cvec (pre-zeroed)
__global__ __launch_bounds__(512) void k23_atomic(const float* __restrict__ xsum,
                                                  const float* __restrict__ Wk,
                                                  const float* __restrict__ bk,
                                                  const float* __restrict__ Wq,
                                                  const float* __restrict__ bq,
                                                  float* __restrict__ v,
                                                  float* __restrict__ cvec) {
    int w = threadIdx.x >> 6, l = threadIdx.x & 63;
    int b = w;
    int h0 = blockIdx.x * CH;
    const float4* xs4 = (const float4*)(xsum + (size_t)b * cD);
    float4 xr[4];
#pragma unroll
    for (int j = 0; j < 4; ++j) xr[j] = xs4[l + 64 * j];
    float4 vacc[4];
#pragma unroll
    for (int j = 0; j < 4; ++j) vacc[j] = make_float4(0.f, 0.f, 0.f, 0.f);
    float cacc = 0.f;
    for (int i = 0; i < CH; ++i) {
        int h = h0 + i;
        const float4* wk4 = (const float4*)(Wk + (size_t)h * cD);
        float pd = 0.f;
#pragma unroll
        for (int j = 0; j < 4; ++j) pd += dot4(wk4[l + 64 * j], xr[j]);
#pragma unroll
        for (int off = 32; off; off >>= 1) pd += __shfl_xor(pd, off);
        float ks = pd + (float)cN * bk[h];
        cacc += bq[h] * ks;
        const float4* wq4 = (const float4*)(Wq + (size_t)h * cD);
#pragma unroll
        for (int j = 0; j < 4; ++j) {
            float4 q = wq4[l + 64 * j];
            vacc[j].x = fmaf(q.x, ks, vacc[j].x);
            vacc[j].y = fmaf(q.y, ks, vacc[j].y);
            vacc[j].z = fmaf(q.z, ks, vacc[j].z);
            vacc[j].w = fmaf(q.w, ks, vacc[j].w);
        }
    }
    float* vb = v + (size_t)b * cD;
#pragma unroll
    for (int j = 0; j < 4; ++j) {
        int d = 4 * (l + 64 * j);
        atomicAdd(vb + d + 0, vacc[j].x);
        atomicAdd(vb + d + 1, vacc[j].y);
        atomicAdd(vb + d + 2, vacc[j].z);
        atomicAdd(vb + d + 3, vacc[j].w);
    }
    if (l == 0) atomicAdd(&cvec[b], cacc);
}

// kred: v[b][d] = sum_hs vpart[hs][b][d];  c[b] = sum_hs cpart[hs][b]
__global__ __launch_bounds__(256) void kred(const float* __restrict__ vpart,
                                            const float* __restrict__ cpart,
                                            float* __restrict__ v,
                                            float* __restrict__ cvec) {
    int idx = blockIdx.x * blockDim.x + threadIdx.x;  // b*cD + d, total 8192
    float acc = 0.f;
    for (int hs = 0; hs < HS; ++hs) acc += vpart[(size_t)hs * cB * cD + idx];
    v[idx] = acc;
    if (blockIdx.x == 0 && threadIdx.x < cB) {
        float a = 0.f;
        for (int hs = 0; hs < HS; ++hs) a += cpart[hs * cB + threadIdx.x];
        cvec[threadIdx.x] = a;
    }
}

// ---------------------------------------------------------------------------
// k4: scores[b][n] = (x[b,n]·v[b] + c[b]) * (1/(N*sqrt(H)))
__global__ __launch_bounds__(256) void k4_scores(const float* __restrict__ x,
                                                 const float* __restrict__ v,
                                                 const float* __restrict__ cvec,
                                                 float* __restrict__ out) {
    int row0 = blockIdx.x * 16;
    int b = row0 / cN;
    __shared__ float4 vs[cD / 4];
    int t = threadIdx.x;
    vs[t] = ((const float4*)(v + (size_t)b * cD))[t];
    __syncthreads();
    int w = t >> 6, l = t & 63;
    float4 vv[4];
#pragma unroll
    for (int j = 0; j < 4; ++j) vv[j] = vs[l + 64 * j];
    float cb = cvec[b];
    const float scale = (1.0f / 4096.0f) * (1.0f / sqrtf(1792.0f));
    int row = row0 + w * 4;
#pragma unroll
    for (int rp = 0; rp < 2; ++rp) {
        const float4* xa = (const float4*)(x + (size_t)(row + 2 * rp) * cD);
        const float4* xb = (const float4*)(x + (size_t)(row + 2 * rp + 1) * cD);
        float a0 = 0.f, a1 = 0.f;
#pragma unroll
        for (int j = 0; j < 4; ++j) {
            a0 += dot4(xa[l + 64 * j], vv[j]);
            a1 += dot4(xb[l + 64 * j], vv[j]);
        }
#pragma unroll
        for (int off = 32; off; off >>= 1) {
            a0 += __shfl_xor(a0, off);
            a1 += __shfl_xor(a1, off);
        }
        if (l == 0) {
            out[row + 2 * rp]     = (a0 + cb) * scale;
            out[row + 2 * rp + 1] = (a1 + cb) * scale;
        }
    }
}

// ---------------------------------------------------------------------------
extern "C" void kernel_launch(void* const* d_in, const int* in_sizes, int n_in,
                              void* d_out, int out_size, void* d_ws, size_t ws_size,
                              hipStream_t stream) {
    const float* x  = (const float*)d_in[0];
    const float* Wq = (const float*)d_in[1];
    const float* bq = (const float*)d_in[2];
    const float* Wk = (const float*)d_in[3];
    const float* bk = (const float*)d_in[4];
    float* out = (float*)d_out;
    float* ws  = (float*)d_ws;

    float* xsum  = ws + OFF_XSUM;
    float* v     = ws + OFF_V;
    float* cvec  = ws + OFF_C;
    float* cpart = ws + OFF_CPART;
    float* vpart = ws + OFF_VPART;
    float* part  = ws + OFF_PART;

    const bool det = ws_size >= TOTAL_DET_FLOATS * sizeof(float);

    if (det) {
        k1a_partial<<<cB * NSPLIT, 256, 0, stream>>>(x, part);
        k1b_reduce<<<(cB * cD) / 256, 256, 0, stream>>>(part, xsum);
        k23_fused<<<HS, 512, 0, stream>>>(xsum, Wk, bk, Wq, bq, vpart, cpart);
        kred<<<(cB * cD) / 256, 256, 0, stream>>>(vpart, cpart, v, cvec);
    } else {
        hipMemsetAsync(d_ws, 0, SMALL_FLOATS * sizeof(float), stream);
        k1_atomic<<<cB * NSPLIT, 256, 0, stream>>>(x, xsum);
        k23_atomic<<<HS, 512, 0, stream>>>(xsum, Wk, bk, Wq, bq, v, cvec);
    }

    k4_scores<<<(cB * cN) / 16, 256, 0, stream>>>(x, v, cvec, out);

    // ---- PROBE (deterministic, idempotent duplicates for timing split) ----
    // Re-running k1a rewrites `part` with identical values (part is not read
    // afterwards); re-running k4 rewrites `out` with identical values.
    // dur_us_round5 - dur_us_round2 - ~4us  ==  t(k1a) + t(k4)  (steady-state
    // cache conditions). This measures the two x-streamers with zero new code.
    if (det) {
        k1a_partial<<<cB * NSPLIT, 256, 0, stream>>>(x, part);
    }
    k4_scores<<<(cB * cN) / 16, 256, 0, stream>>>(x, v, cvec, out);
}

// Round 6
// 81.913 us; speedup vs baseline: 2.7427x; 1.3867x over previous
//
#include <hip/hip_runtime.h>

// Problem constants (match reference)
constexpr int cB = 8;
constexpr int cN = 4096;
constexpr int cD = 1024;   // IN_FEATURES
constexpr int cH = 1792;   // HIDDEN_DIM

constexpr int NB1 = 256;        // K1a blocks: 128 rows each, LDS-reduced
constexpr int CH  = 8;          // K23: h-values per block
constexpr int HS  = cH / CH;    // 224 blocks

// Workspace layout (floats)
constexpr size_t OFF_XSUM  = 0;                                   // 8192
constexpr size_t OFF_V     = OFF_XSUM + (size_t)cB * cD;          // 8192
constexpr size_t OFF_C     = OFF_V + (size_t)cB * cD;             // 8 (pad 64)
constexpr size_t OFF_CPART = OFF_C + 64;                          // HS*B = 1792 (pad 2048)
constexpr size_t OFF_VPART = OFF_CPART + 2048;                    // HS*B*D = 1,835,008
constexpr size_t OFF_PART  = OFF_VPART + (size_t)HS * cB * cD;    // NB1*D = 262,144
constexpr size_t TOTAL_DET_FLOATS = OFF_PART + (size_t)NB1 * cD;  // ~2.12M floats (~8.5MB)
constexpr size_t SMALL_FLOATS     = OFF_CPART;                    // atomic-fallback region

__device__ __forceinline__ float dot4(float4 a, float4 b) {
    return a.x * b.x + a.y * b.y + a.z * b.z + a.w * b.w;
}

// ---------------------------------------------------------------------------
// K1a: part[g][d] = sum of 128 consecutive rows of x (g = b*32 + ns).
// 1024 threads: 4 row-groups x 256 cols, LDS-reduced to ONE partial per block.
__global__ __launch_bounds__(1024) void K1a(const float* __restrict__ x,
                                            float* __restrict__ part) {
    __shared__ float4 lds[1024];
    int g = blockIdx.x;                  // 0..255
    int b = g >> 5, ns = g & 31;
    int t = threadIdx.x;
    int rg = t >> 8, col = t & 255;      // row-group 0..3, float4 column
    const float4* xp = (const float4*)(x + ((size_t)b * cN + (size_t)ns * 128 + rg) * cD) + col;
    float4 acc = make_float4(0.f, 0.f, 0.f, 0.f);
#pragma unroll 8
    for (int k = 0; k < 32; ++k) {       // rows rg, rg+4, ..., rg+124
        float4 v2 = xp[(size_t)k * 4 * (cD / 4)];
        acc.x += v2.x; acc.y += v2.y; acc.z += v2.z; acc.w += v2.w;
    }
    lds[rg * 256 + col] = acc;
    __syncthreads();
    if (rg == 0) {
        float4 a0 = lds[col], a1 = lds[256 + col], a2 = lds[512 + col], a3 = lds[768 + col];
        float4 s;
        s.x = (a0.x + a1.x) + (a2.x + a3.x);
        s.y = (a0.y + a1.y) + (a2.y + a3.y);
        s.z = (a0.z + a1.z) + (a2.z + a3.z);
        s.w = (a0.w + a1.w) + (a2.w + a3.w);
        ((float4*)(part + (size_t)g * cD))[col] = s;
    }
}

// K1b: xsum[b][d] = sum over 32 partials (part is only 1 MB now).
__global__ __launch_bounds__(128) void K1b(const float* __restrict__ part,
                                           float* __restrict__ xsum) {
    int idx = blockIdx.x * 128 + threadIdx.x;   // 0..8191 = b*cD + d
    int b = idx >> 10, d = idx & 1023;
    const float* p = part + (size_t)b * 32 * cD + d;
    float a0 = 0.f, a1 = 0.f, a2 = 0.f, a3 = 0.f;
#pragma unroll
    for (int k = 0; k < 32; k += 4) {
        a0 += p[(size_t)(k + 0) * cD];
        a1 += p[(size_t)(k + 1) * cD];
        a2 += p[(size_t)(k + 2) * cD];
        a3 += p[(size_t)(k + 3) * cD];
    }
    xsum[idx] = (a0 + a1) + (a2 + a3);
}

// K1 fallback: LDS-reduced partial -> atomics into xsum (pre-zeroed)
__global__ __launch_bounds__(1024) void K1_atomic(const float* __restrict__ x,
                                                  float* __restrict__ xsum) {
    __shared__ float4 lds[1024];
    int g = blockIdx.x;
    int b = g >> 5, ns = g & 31;
    int t = threadIdx.x;
    int rg = t >> 8, col = t & 255;
    const float4* xp = (const float4*)(x + ((size_t)b * cN + (size_t)ns * 128 + rg) * cD) + col;
    float4 acc = make_float4(0.f, 0.f, 0.f, 0.f);
#pragma unroll 8
    for (int k = 0; k < 32; ++k) {
        float4 v2 = xp[(size_t)k * 4 * (cD / 4)];
        acc.x += v2.x; acc.y += v2.y; acc.z += v2.z; acc.w += v2.w;
    }
    lds[rg * 256 + col] = acc;
    __syncthreads();
    if (rg == 0) {
        float4 a0 = lds[col], a1 = lds[256 + col], a2 = lds[512 + col], a3 = lds[768 + col];
        float* dst = xsum + (size_t)b * cD + 4 * col;
        atomicAdd(dst + 0, (a0.x + a1.x) + (a2.x + a3.x));
        atomicAdd(dst + 1, (a0.y + a1.y) + (a2.y + a3.y));
        atomicAdd(dst + 2, (a0.z + a1.z) + (a2.z + a3.z));
        atomicAdd(dst + 3, (a0.w + a1.w) + (a2.w + a3.w));
    }
}

// ---------------------------------------------------------------------------
// K23: fused ksum -> (vpart, cpart).  Grid = HS(224) blocks x 512 threads.
// Wave w = batch b; block handles h in [blockIdx*CH, +CH).
__global__ __launch_bounds__(512) void K23(const float* __restrict__ xsum,
                                           const float* __restrict__ Wk,
                                           const float* __restrict__ bk,
                                           const float* __restrict__ Wq,
                                           const float* __restrict__ bq,
                                           float* __restrict__ vpart,
                                           float* __restrict__ cpart) {
    int w = threadIdx.x >> 6, l = threadIdx.x & 63;
    int b = w;
    int h0 = blockIdx.x * CH;

    const float4* xs4 = (const float4*)(xsum + (size_t)b * cD);
    float4 xr[4];
#pragma unroll
    for (int j = 0; j < 4; ++j) xr[j] = xs4[l + 64 * j];

    float4 vacc[4];
#pragma unroll
    for (int j = 0; j < 4; ++j) vacc[j] = make_float4(0.f, 0.f, 0.f, 0.f);
    float cacc = 0.f;

    for (int i = 0; i < CH; i += 2) {   // 2-way interleaved reduce chains
        int ha = h0 + i, hb = h0 + i + 1;
        const float4* wka = (const float4*)(Wk + (size_t)ha * cD);
        const float4* wkb = (const float4*)(Wk + (size_t)hb * cD);
        float pa = 0.f, pb = 0.f;
#pragma unroll
        for (int j = 0; j < 4; ++j) {
            pa += dot4(wka[l + 64 * j], xr[j]);
            pb += dot4(wkb[l + 64 * j], xr[j]);
        }
#pragma unroll
        for (int off = 32; off; off >>= 1) {
            pa += __shfl_xor(pa, off);
            pb += __shfl_xor(pb, off);
        }
        float ksa = pa + (float)cN * bk[ha];
        float ksb = pb + (float)cN * bk[hb];
        cacc += bq[ha] * ksa + bq[hb] * ksb;
        const float4* wqa = (const float4*)(Wq + (size_t)ha * cD);
        const float4* wqb = (const float4*)(Wq + (size_t)hb * cD);
#pragma unroll
        for (int j = 0; j < 4; ++j) {
            float4 qa = wqa[l + 64 * j];
            float4 qb = wqb[l + 64 * j];
            vacc[j].x = fmaf(qa.x, ksa, fmaf(qb.x, ksb, vacc[j].x));
            vacc[j].y = fmaf(qa.y, ksa, fmaf(qb.y, ksb, vacc[j].y));
            vacc[j].z = fmaf(qa.z, ksa, fmaf(qb.z, ksb, vacc[j].z));
            vacc[j].w = fmaf(qa.w, ksa, fmaf(qb.w, ksb, vacc[j].w));
        }
    }

    float4* vp = (float4*)(vpart + ((size_t)blockIdx.x * cB + b) * cD);
#pragma unroll
    for (int j = 0; j < 4; ++j) vp[l + 64 * j] = vacc[j];
    if (l == 0) cpart[blockIdx.x * cB + b] = cacc;
}

// K23 fallback: atomics into v, cvec (pre-zeroed)
__global__ __launch_bounds__(512) void K23_atomic(const float* __restrict__ xsum,
                                                  const float* __restrict__ Wk,
                                                  const float* __restrict__ bk,
                                                  const float* __restrict__ Wq,
                                                  const float* __restrict__ bq,
                                                  float* __restrict__ v,
                                                  float* __restrict__ cvec) {
    int w = threadIdx.x >> 6, l = threadIdx.x & 63;
    int b = w;
    int h0 = blockIdx.x * CH;
    const float4* xs4 = (const float4*)(xsum + (size_t)b * cD);
    float4 xr[4];
#pragma unroll
    for (int j = 0; j < 4; ++j) xr[j] = xs4[l + 64 * j];
    float4 vacc[4];
#pragma unroll
    for (int j = 0; j < 4; ++j) vacc[j] = make_float4(0.f, 0.f, 0.f, 0.f);
    float cacc = 0.f;
    for (int i = 0; i < CH; ++i) {
        int h = h0 + i;
        const float4* wk4 = (const float4*)(Wk + (size_t)h * cD);
        float pd = 0.f;
#pragma unroll
        for (int j = 0; j < 4; ++j) pd += dot4(wk4[l + 64 * j], xr[j]);
#pragma unroll
        for (int off = 32; off; off >>= 1) pd += __shfl_xor(pd, off);
        float ks = pd + (float)cN * bk[h];
        cacc += bq[h] * ks;
        const float4* wq4 = (const float4*)(Wq + (size_t)h * cD);
#pragma unroll
        for (int j = 0; j < 4; ++j) {
            float4 q = wq4[l + 64 * j];
            vacc[j].x = fmaf(q.x, ks, vacc[j].x);
            vacc[j].y = fmaf(q.y, ks, vacc[j].y);
            vacc[j].z = fmaf(q.z, ks, vacc[j].z);
            vacc[j].w = fmaf(q.w, ks, vacc[j].w);
        }
    }
    float* vb = v + (size_t)b * cD;
#pragma unroll
    for (int j = 0; j < 4; ++j) {
        int d = 4 * (l + 64 * j);
        atomicAdd(vb + d + 0, vacc[j].x);
        atomicAdd(vb + d + 1, vacc[j].y);
        atomicAdd(vb + d + 2, vacc[j].z);
        atomicAdd(vb + d + 3, vacc[j].w);
    }
    if (l == 0) atomicAdd(&cvec[b], cacc);
}

// Kred: v[b][d] = sum_hs vpart[hs][b][d];  c[b] = sum_hs cpart[hs][b]
__global__ __launch_bounds__(128) void Kred(const float* __restrict__ vpart,
                                            const float* __restrict__ cpart,
                                            float* __restrict__ v,
                                            float* __restrict__ cvec) {
    int idx = blockIdx.x * 128 + threadIdx.x;   // b*cD + d, total 8192
    const float* p = vpart + idx;
    float a0 = 0.f, a1 = 0.f, a2 = 0.f, a3 = 0.f;
#pragma unroll 4
    for (int hs = 0; hs < HS; hs += 4) {
        a0 += p[(size_t)(hs + 0) * cB * cD];
        a1 += p[(size_t)(hs + 1) * cB * cD];
        a2 += p[(size_t)(hs + 2) * cB * cD];
        a3 += p[(size_t)(hs + 3) * cB * cD];
    }
    v[idx] = (a0 + a1) + (a2 + a3);
    if (blockIdx.x == 0 && threadIdx.x < cB) {
        float a = 0.f;
        for (int hs = 0; hs < HS; ++hs) a += cpart[hs * cB + threadIdx.x];
        cvec[threadIdx.x] = a;
    }
}

// ---------------------------------------------------------------------------
// K4: scores[b][n] = (x[b,n]·v[b] + c[b]) * (1/(N*sqrt(H)))
__global__ __launch_bounds__(256) void K4(const float* __restrict__ x,
                                          const float* __restrict__ v,
                                          const float* __restrict__ cvec,
                                          float* __restrict__ out) {
    int row0 = blockIdx.x * 16;
    int b = row0 / cN;
    __shared__ float4 vs[cD / 4];
    int t = threadIdx.x;
    vs[t] = ((const float4*)(v + (size_t)b * cD))[t];
    __syncthreads();
    int w = t >> 6, l = t & 63;
    float4 vv[4];
#pragma unroll
    for (int j = 0; j < 4; ++j) vv[j] = vs[l + 64 * j];
    float cb = cvec[b];
    const float scale = (1.0f / 4096.0f) * (1.0f / sqrtf(1792.0f));
    int row = row0 + w * 4;
#pragma unroll
    for (int rp = 0; rp < 2; ++rp) {
        const float4* xa = (const float4*)(x + (size_t)(row + 2 * rp) * cD);
        const float4* xb = (const float4*)(x + (size_t)(row + 2 * rp + 1) * cD);
        float a0 = 0.f, a1 = 0.f;
#pragma unroll
        for (int j = 0; j < 4; ++j) {
            a0 += dot4(xa[l + 64 * j], vv[j]);
            a1 += dot4(xb[l + 64 * j], vv[j]);
        }
#pragma unroll
        for (int off = 32; off; off >>= 1) {
            a0 += __shfl_xor(a0, off);
            a1 += __shfl_xor(a1, off);
        }
        if (l == 0) {
            out[row + 2 * rp]     = (a0 + cb) * scale;
            out[row + 2 * rp + 1] = (a1 + cb) * scale;
        }
    }
}

// ---------------------------------------------------------------------------
extern "C" void kernel_launch(void* const* d_in, const int* in_sizes, int n_in,
                              void* d_out, int out_size, void* d_ws, size_t ws_size,
                              hipStream_t stream) {
    const float* x  = (const float*)d_in[0];
    const float* Wq = (const float*)d_in[1];
    const float* bq = (const float*)d_in[2];
    const float* Wk = (const float*)d_in[3];
    const float* bk = (const float*)d_in[4];
    float* out = (float*)d_out;
    float* ws  = (float*)d_ws;

    float* xsum  = ws + OFF_XSUM;
    float* v     = ws + OFF_V;
    float* cvec  = ws + OFF_C;
    float* cpart = ws + OFF_CPART;
    float* vpart = ws + OFF_VPART;
    float* part  = ws + OFF_PART;

    const bool det = ws_size >= TOTAL_DET_FLOATS * sizeof(float);

    if (det) {
        K1a<<<NB1, 1024, 0, stream>>>(x, part);                       // x pass 1 (HBM)
        K1b<<<(cB * cD) / 128, 128, 0, stream>>>(part, xsum);         // 1 MB reduce
        K23<<<HS, 512, 0, stream>>>(xsum, Wk, bk, Wq, bq, vpart, cpart); // weights once
        Kred<<<(cB * cD) / 128, 128, 0, stream>>>(vpart, cpart, v, cvec); // 7.3 MB reduce
    } else {
        hipMemsetAsync(d_ws, 0, SMALL_FLOATS * sizeof(float), stream);
        K1_atomic<<<NB1, 1024, 0, stream>>>(x, xsum);
        K23_atomic<<<HS, 512, 0, stream>>>(xsum, Wk, bk, Wq, bq, v, cvec);
    }

    K4<<<(cB * cN) / 16, 256, 0, stream>>>(x, v, cvec, out);          // x pass 2 (L3-warm)
}

// Round 7
// 69.524 us; speedup vs baseline: 3.2315x; 1.1782x over previous
//
#include <hip/hip_runtime.h>

// Problem constants (match reference)
constexpr int cB = 8;
constexpr int cN = 4096;
constexpr int cD = 1024;   // IN_FEATURES
constexpr int cH = 1792;   // HIDDEN_DIM

constexpr int NSPLIT = 128;     // k1a: partials per batch (32 rows per block)
constexpr int CH     = 8;       // k23: h-values per block
constexpr int HS     = cH / CH; // 224 blocks

// Workspace layout (floats)
constexpr size_t OFF_XSUM  = 0;                                   // 8192
constexpr size_t OFF_V     = OFF_XSUM + (size_t)cB * cD;          // 8192
constexpr size_t OFF_C     = OFF_V + (size_t)cB * cD;             // 8 (pad 64)
constexpr size_t OFF_CPART = OFF_C + 64;                          // HS*B = 1792 (pad 2048)
constexpr size_t OFF_VPART = OFF_CPART + 2048;                    // HS*B*D = 1,835,008
constexpr size_t OFF_PART  = OFF_VPART + (size_t)HS * cB * cD;    // B*NSPLIT*D = 1,048,576
constexpr size_t TOTAL_DET_FLOATS = OFF_PART + (size_t)cB * NSPLIT * cD;  // ~2.9M (~11.6MB)
constexpr size_t SMALL_FLOATS     = OFF_CPART;                    // atomic-fallback region

__device__ __forceinline__ float dot4(float4 a, float4 b) {
    return a.x * b.x + a.y * b.y + a.z * b.z + a.w * b.w;
}

// ---------------------------------------------------------------------------
// k1a (round-2 shape, 78.4us baseline): part[b*128+ns][d] = sum of 32 rows.
__global__ __launch_bounds__(256) void k1a_partial(const float* __restrict__ x,
                                                   float* __restrict__ part) {
    int bid = blockIdx.x;                 // 0 .. B*NSPLIT-1 = 1023
    int b = bid / NSPLIT, ns = bid % NSPLIT;
    const int rows = cN / NSPLIT;         // 32
    const float4* xp = (const float4*)(x + ((size_t)b * cN + (size_t)ns * rows) * cD);
    int t = threadIdx.x;                  // one float4 column of the row
    float4 acc = make_float4(0.f, 0.f, 0.f, 0.f);
    for (int r = 0; r < rows; ++r) {
        float4 v = xp[(size_t)r * (cD / 4) + t];
        acc.x += v.x; acc.y += v.y; acc.z += v.z; acc.w += v.w;
    }
    ((float4*)part)[(size_t)bid * (cD / 4) + t] = acc;
}

// k1b NEW: wave-per-output. 8192 outputs, 8 waves/block -> 1024 blocks.
// lane l sums partials ns = l and l+64 (all independent 4B loads), then
// 6-step shfl_xor tree. Massive TLP hides the strided-load latency.
__global__ __launch_bounds__(512) void k1b_wave(const float* __restrict__ part,
                                                float* __restrict__ xsum) {
    int w = threadIdx.x >> 6, l = threadIdx.x & 63;
    int idx = blockIdx.x * 8 + w;          // 0..8191 = b*cD + d
    int b = idx >> 10, d = idx & 1023;
    const float* p = part + (size_t)b * NSPLIT * cD + d;
    float acc = p[(size_t)l * cD] + p[(size_t)(l + 64) * cD];
#pragma unroll
    for (int off = 32; off; off >>= 1) acc += __shfl_xor(acc, off);
    if (l == 0) xsum[idx] = acc;
}

// k1 fallback: atomic accumulate directly into xsum (pre-zeroed)
__global__ __launch_bounds__(256) void k1_atomic(const float* __restrict__ x,
                                                 float* __restrict__ xsum) {
    int bid = blockIdx.x;
    int b = bid / NSPLIT, ns = bid % NSPLIT;
    const int rows = cN / NSPLIT;
    const float4* xp = (const float4*)(x + ((size_t)b * cN + (size_t)ns * rows) * cD);
    int t = threadIdx.x;
    float4 acc = make_float4(0.f, 0.f, 0.f, 0.f);
    for (int r = 0; r < rows; ++r) {
        float4 v = xp[(size_t)r * (cD / 4) + t];
        acc.x += v.x; acc.y += v.y; acc.z += v.z; acc.w += v.w;
    }
    float* dst = xsum + (size_t)b * cD + t * 4;
    atomicAdd(dst + 0, acc.x);
    atomicAdd(dst + 1, acc.y);
    atomicAdd(dst + 2, acc.z);
    atomicAdd(dst + 3, acc.w);
}

// ---------------------------------------------------------------------------
// k23: fused ksum -> (vpart, cpart).  Grid = HS(224) blocks x 512 threads.
__global__ __launch_bounds__(512) void k23_fused(const float* __restrict__ xsum,
                                                 const float* __restrict__ Wk,
                                                 const float* __restrict__ bk,
                                                 const float* __restrict__ Wq,
                                                 const float* __restrict__ bq,
                                                 float* __restrict__ vpart,
                                                 float* __restrict__ cpart) {
    int w = threadIdx.x >> 6, l = threadIdx.x & 63;
    int b = w;                       // 8 waves == 8 batches
    int h0 = blockIdx.x * CH;

    const float4* xs4 = (const float4*)(xsum + (size_t)b * cD);
    float4 xr[4];
#pragma unroll
    for (int j = 0; j < 4; ++j) xr[j] = xs4[l + 64 * j];

    float4 vacc[4];
#pragma unroll
    for (int j = 0; j < 4; ++j) vacc[j] = make_float4(0.f, 0.f, 0.f, 0.f);
    float cacc = 0.f;

    for (int i = 0; i < CH; i += 2) {   // 2-way interleaved reduce chains
        int ha = h0 + i, hb = h0 + i + 1;
        const float4* wka = (const float4*)(Wk + (size_t)ha * cD);
        const float4* wkb = (const float4*)(Wk + (size_t)hb * cD);
        float pa = 0.f, pb = 0.f;
#pragma unroll
        for (int j = 0; j < 4; ++j) {
            pa += dot4(wka[l + 64 * j], xr[j]);
            pb += dot4(wkb[l + 64 * j], xr[j]);
        }
#pragma unroll
        for (int off = 32; off; off >>= 1) {
            pa += __shfl_xor(pa, off);
            pb += __shfl_xor(pb, off);
        }
        float ksa = pa + (float)cN * bk[ha];
        float ksb = pb + (float)cN * bk[hb];
        cacc += bq[ha] * ksa + bq[hb] * ksb;
        const float4* wqa = (const float4*)(Wq + (size_t)ha * cD);
        const float4* wqb = (const float4*)(Wq + (size_t)hb * cD);
#pragma unroll
        for (int j = 0; j < 4; ++j) {
            float4 qa = wqa[l + 64 * j];
            float4 qb = wqb[l + 64 * j];
            vacc[j].x = fmaf(qa.x, ksa, fmaf(qb.x, ksb, vacc[j].x));
            vacc[j].y = fmaf(qa.y, ksa, fmaf(qb.y, ksb, vacc[j].y));
            vacc[j].z = fmaf(qa.z, ksa, fmaf(qb.z, ksb, vacc[j].z));
            vacc[j].w = fmaf(qa.w, ksa, fmaf(qb.w, ksb, vacc[j].w));
        }
    }

    float4* vp = (float4*)(vpart + ((size_t)blockIdx.x * cB + b) * cD);
#pragma unroll
    for (int j = 0; j < 4; ++j) vp[l + 64 * j] = vacc[j];
    if (l == 0) cpart[blockIdx.x * cB + b] = cacc;
}

// k23 fallback: atomics into v, cvec (pre-zeroed)
__global__ __launch_bounds__(512) void k23_atomic(const float* __restrict__ xsum,
                                                  const float* __restrict__ Wk,
                                                  const float* __restrict__ bk,
                                                  const float* __restrict__ Wq,
                                                  const float* __restrict__ bq,
                                                  float* __restrict__ v,
                                                  float* __restrict__ cvec) {
    int w = threadIdx.x >> 6, l = threadIdx.x & 63;
    int b = w;
    int h0 = blockIdx.x * CH;
    const float4* xs4 = (const float4*)(xsum + (size_t)b * cD);
    float4 xr[4];
#pragma unroll
    for (int j = 0; j < 4; ++j) xr[j] = xs4[l + 64 * j];
    float4 vacc[4];
#pragma unroll
    for (int j = 0; j < 4; ++j) vacc[j] = make_float4(0.f, 0.f, 0.f, 0.f);
    float cacc = 0.f;
    for (int i = 0; i < CH; ++i) {
        int h = h0 + i;
        const float4* wk4 = (const float4*)(Wk + (size_t)h * cD);
        float pd = 0.f;
#pragma unroll
        for (int j = 0; j < 4; ++j) pd += dot4(wk4[l + 64 * j], xr[j]);
#pragma unroll
        for (int off = 32; off; off >>= 1) pd += __shfl_xor(pd, off);
        float ks = pd + (float)cN * bk[h];
        cacc += bq[h] * ks;
        const float4* wq4 = (const float4*)(Wq + (size_t)h * cD);
#pragma unroll
        for (int j = 0; j < 4; ++j) {
            float4 q = wq4[l + 64 * j];
            vacc[j].x = fmaf(q.x, ks, vacc[j].x);
            vacc[j].y = fmaf(q.y, ks, vacc[j].y);
            vacc[j].z = fmaf(q.z, ks, vacc[j].z);
            vacc[j].w = fmaf(q.w, ks, vacc[j].w);
        }
    }
    float* vb = v + (size_t)b * cD;
#pragma unroll
    for (int j = 0; j < 4; ++j) {
        int d = 4 * (l + 64 * j);
        atomicAdd(vb + d + 0, vacc[j].x);
        atomicAdd(vb + d + 1, vacc[j].y);
        atomicAdd(vb + d + 2, vacc[j].z);
        atomicAdd(vb + d + 3, vacc[j].w);
    }
    if (l == 0) atomicAdd(&cvec[b], cacc);
}

// kred NEW: wave-per-output over 224 partials; block 1024 reduces cpart.
// lane l sums hs = l, l+64, l+128, l+192 (<224) -> <=4 independent loads,
// then shfl tree. 8192 waves of TLP.
__global__ __launch_bounds__(512) void kred_wave(const float* __restrict__ vpart,
                                                 const float* __restrict__ cpart,
                                                 float* __restrict__ v,
                                                 float* __restrict__ cvec) {
    int w = threadIdx.x >> 6, l = threadIdx.x & 63;
    if (blockIdx.x < 1024) {
        int idx = blockIdx.x * 8 + w;      // 0..8191 = b*cD + d
        const float* p = vpart + idx;
        float acc = 0.f;
#pragma unroll
        for (int k = 0; k < 4; ++k) {
            int hs = l + 64 * k;
            if (hs < HS) acc += p[(size_t)hs * (cB * cD)];
        }
#pragma unroll
        for (int off = 32; off; off >>= 1) acc += __shfl_xor(acc, off);
        if (l == 0) v[idx] = acc;
    } else {
        // cvec: wave w handles batch b=w (waves 0..7)
        if (w < cB) {
            float acc = 0.f;
#pragma unroll
            for (int k = 0; k < 4; ++k) {
                int hs = l + 64 * k;
                if (hs < HS) acc += cpart[hs * cB + w];
            }
#pragma unroll
            for (int off = 32; off; off >>= 1) acc += __shfl_xor(acc, off);
            if (l == 0) cvec[w] = acc;
        }
    }
}

// ---------------------------------------------------------------------------
// k4 (round-2 shape): scores[b][n] = (x[b,n]·v[b] + c[b]) * (1/(N*sqrt(H)))
__global__ __launch_bounds__(256) void k4_scores(const float* __restrict__ x,
                                                 const float* __restrict__ v,
                                                 const float* __restrict__ cvec,
                                                 float* __restrict__ out) {
    int row0 = blockIdx.x * 16;
    int b = row0 / cN;
    __shared__ float4 vs[cD / 4];
    int t = threadIdx.x;
    vs[t] = ((const float4*)(v + (size_t)b * cD))[t];
    __syncthreads();
    int w = t >> 6, l = t & 63;
    float4 vv[4];
#pragma unroll
    for (int j = 0; j < 4; ++j) vv[j] = vs[l + 64 * j];
    float cb = cvec[b];
    const float scale = (1.0f / 4096.0f) * (1.0f / sqrtf(1792.0f));
    int row = row0 + w * 4;
#pragma unroll
    for (int rp = 0; rp < 2; ++rp) {
        const float4* xa = (const float4*)(x + (size_t)(row + 2 * rp) * cD);
        const float4* xb = (const float4*)(x + (size_t)(row + 2 * rp + 1) * cD);
        float a0 = 0.f, a1 = 0.f;
#pragma unroll
        for (int j = 0; j < 4; ++j) {
            a0 += dot4(xa[l + 64 * j], vv[j]);
            a1 += dot4(xb[l + 64 * j], vv[j]);
        }
#pragma unroll
        for (int off = 32; off; off >>= 1) {
            a0 += __shfl_xor(a0, off);
            a1 += __shfl_xor(a1, off);
        }
        if (l == 0) {
            out[row + 2 * rp]     = (a0 + cb) * scale;
            out[row + 2 * rp + 1] = (a1 + cb) * scale;
        }
    }
}

// ---------------------------------------------------------------------------
extern "C" void kernel_launch(void* const* d_in, const int* in_sizes, int n_in,
                              void* d_out, int out_size, void* d_ws, size_t ws_size,
                              hipStream_t stream) {
    const float* x  = (const float*)d_in[0];
    const float* Wq = (const float*)d_in[1];
    const float* bq = (const float*)d_in[2];
    const float* Wk = (const float*)d_in[3];
    const float* bk = (const float*)d_in[4];
    float* out = (float*)d_out;
    float* ws  = (float*)d_ws;

    float* xsum  = ws + OFF_XSUM;
    float* v     = ws + OFF_V;
    float* cvec  = ws + OFF_C;
    float* cpart = ws + OFF_CPART;
    float* vpart = ws + OFF_VPART;
    float* part  = ws + OFF_PART;

    const bool det = ws_size >= TOTAL_DET_FLOATS * sizeof(float);

    if (det) {
        k1a_partial<<<cB * NSPLIT, 256, 0, stream>>>(x, part);          // x pass 1 (HBM)
        k1b_wave<<<1024, 512, 0, stream>>>(part, xsum);                 // wave-per-output
        k23_fused<<<HS, 512, 0, stream>>>(xsum, Wk, bk, Wq, bq, vpart, cpart);
        kred_wave<<<1025, 512, 0, stream>>>(vpart, cpart, v, cvec);     // wave-per-output
    } else {
        hipMemsetAsync(d_ws, 0, SMALL_FLOATS * sizeof(float), stream);
        k1_atomic<<<cB * NSPLIT, 256, 0, stream>>>(x, xsum);
        k23_atomic<<<HS, 512, 0, stream>>>(xsum, Wk, bk, Wq, bq, v, cvec);
    }

    k4_scores<<<(cB * cN) / 16, 256, 0, stream>>>(x, v, cvec, out);     // x pass 2
}

// Round 8
// 65.885 us; speedup vs baseline: 3.4100x; 1.0552x over previous
//
#include <hip/hip_runtime.h>

// Problem constants (match reference)
constexpr int cB = 8;
constexpr int cN = 4096;
constexpr int cD = 1024;   // IN_FEATURES
constexpr int cH = 1792;   // HIDDEN_DIM

// Workspace layout (floats)
constexpr size_t OFF_XSUM  = 0;                               // 8192
constexpr size_t OFF_KSUM  = OFF_XSUM + (size_t)cB * cD;      // 14336
constexpr size_t OFF_V     = OFF_KSUM + (size_t)cB * cH;      // 8192
constexpr size_t OFF_C     = OFF_V + (size_t)cB * cD;         // 8 (pad 64)
constexpr size_t OFF_VP3   = OFF_C + 64;                      // 16*8*1024 = 131072
constexpr size_t OFF_PART2 = OFF_VP3 + (size_t)16 * cB * cD;  // 128*1024 = 131072
constexpr size_t OFF_PART  = OFF_PART2 + (size_t)128 * cD;    // 1024*1024
constexpr size_t TOTAL_DET_FLOATS = OFF_PART + (size_t)1024 * cD;  // ~1.34M (~5.4MB)
constexpr size_t SMALL_FLOATS     = OFF_VP3;                  // atomic-fallback region

__device__ __forceinline__ float dot4(float4 a, float4 b) {
    return a.x * b.x + a.y * b.y + a.z * b.z + a.w * b.w;
}

// ---------------------------------------------------------------------------
// k1a (unchanged, proven): part[b*128+ns][d] = sum of 32 rows of x[b].
__global__ __launch_bounds__(256) void k1a_partial(const float* __restrict__ x,
                                                   float* __restrict__ part) {
    int bid = blockIdx.x;                 // 0..1023
    int b = bid >> 7, ns = bid & 127;
    const float4* xp = (const float4*)(x + ((size_t)b * cN + (size_t)ns * 32) * cD);
    int t = threadIdx.x;
    float4 acc = make_float4(0.f, 0.f, 0.f, 0.f);
    for (int r = 0; r < 32; ++r) {
        float4 v = xp[(size_t)r * (cD / 4) + t];
        acc.x += v.x; acc.y += v.y; acc.z += v.z; acc.w += v.w;
    }
    ((float4*)part)[(size_t)bid * (cD / 4) + t] = acc;
}

// k1bA: contiguous-slab reduce: part2[b*16+s][d] = sum of 8 part rows.
// All loads are f4 with adjacent lanes -> full 64B sectors, zero amplification.
__global__ __launch_bounds__(256) void k1bA(const float* __restrict__ part,
                                            float* __restrict__ part2) {
    int bid = blockIdx.x;                 // 0..127
    int b = bid >> 4, s = bid & 15;
    int t = threadIdx.x;                  // f4 column 0..255
    const float4* p = (const float4*)part + ((size_t)b * 128 + s * 8) * 256 + t;
    float4 a0 = p[0], a1 = p[256], a2 = p[512], a3 = p[768];
    float4 a4 = p[1024], a5 = p[1280], a6 = p[1536], a7 = p[1792];
    float4 r;
    r.x = ((a0.x + a1.x) + (a2.x + a3.x)) + ((a4.x + a5.x) + (a6.x + a7.x));
    r.y = ((a0.y + a1.y) + (a2.y + a3.y)) + ((a4.y + a5.y) + (a6.y + a7.y));
    r.z = ((a0.z + a1.z) + (a2.z + a3.z)) + ((a4.z + a5.z) + (a6.z + a7.z));
    r.w = ((a0.w + a1.w) + (a2.w + a3.w)) + ((a4.w + a5.w) + (a6.w + a7.w));
    ((float4*)part2)[(size_t)(b * 16 + s) * 256 + t] = r;
}

// k1bB: xsum[b][d] = sum of 16 part2 slabs (f4 loads, stride 4KB, full sectors).
__global__ __launch_bounds__(512) void k1bB(const float* __restrict__ part2,
                                            float* __restrict__ xsum) {
    int fidx = blockIdx.x * 512 + threadIdx.x;   // 0..2047 f4 outputs
    int b = fidx >> 8, j = fidx & 255;
    const float4* p = (const float4*)part2 + (size_t)b * 16 * 256 + j;
    float4 acc = make_float4(0.f, 0.f, 0.f, 0.f);
#pragma unroll
    for (int s = 0; s < 16; ++s) {
        float4 v = p[(size_t)s * 256];
        acc.x += v.x; acc.y += v.y; acc.z += v.z; acc.w += v.w;
    }
    ((float4*)xsum)[fidx] = acc;
}

// ---------------------------------------------------------------------------
// KS: ksum[b][h] = xsum[b]·Wk[h] + N*bk[h].  224 blocks x 512 (wave=batch),
// 8 h per block -> Wk read exactly once, 32KB/block.
__global__ __launch_bounds__(512) void KS(const float* __restrict__ xsum,
                                          const float* __restrict__ Wk,
                                          const float* __restrict__ bk,
                                          float* __restrict__ ksum) {
    int w = threadIdx.x >> 6, l = threadIdx.x & 63;
    int b = w;
    int h0 = blockIdx.x * 8;
    const float4* xs4 = (const float4*)(xsum + (size_t)b * cD);
    float4 xr[4];
#pragma unroll
    for (int j = 0; j < 4; ++j) xr[j] = xs4[l + 64 * j];
    for (int i = 0; i < 8; i += 2) {
        int ha = h0 + i, hb = h0 + i + 1;
        const float4* wka = (const float4*)(Wk + (size_t)ha * cD);
        const float4* wkb = (const float4*)(Wk + (size_t)hb * cD);
        float pa = 0.f, pb = 0.f;
#pragma unroll
        for (int j = 0; j < 4; ++j) {
            pa += dot4(wka[l + 64 * j], xr[j]);
            pb += dot4(wkb[l + 64 * j], xr[j]);
        }
#pragma unroll
        for (int off = 32; off; off >>= 1) {
            pa += __shfl_xor(pa, off);
            pb += __shfl_xor(pb, off);
        }
        if (l == 0) {
            ksum[(size_t)b * cH + ha] = pa + (float)cN * bk[ha];
            ksum[(size_t)b * cH + hb] = pb + (float)cN * bk[hb];
        }
    }
}

// ---------------------------------------------------------------------------
// KV: vpart3[hc][b][d] for disjoint (112h x 64d) Wq tiles. 256 blocks x 512.
// Wq read exactly once, coalesced 256B row-chunks; ksum broadcast from LDS.
__global__ __launch_bounds__(512) void KV(const float* __restrict__ ksum,
                                          const float* __restrict__ Wq,
                                          float* __restrict__ vpart3) {
    __shared__ float ks_l[cB][112];
    __shared__ float red[8][cB][64];
    int hc = blockIdx.x >> 4;             // 0..15 (112 h each)
    int dc = blockIdx.x & 15;             // 0..15 (64 d each)
    int t = threadIdx.x;
    for (int i = t; i < cB * 112; i += 512) {
        int b = i / 112, hh = i % 112;
        ks_l[b][hh] = ksum[(size_t)b * cH + hc * 112 + hh];
    }
    __syncthreads();
    int w = t >> 6, l = t & 63;
    int d = dc * 64 + l;
    float vacc[cB];
#pragma unroll
    for (int b = 0; b < cB; ++b) vacc[b] = 0.f;
#pragma unroll 2
    for (int i = 0; i < 14; ++i) {
        int hh = w * 14 + i;
        int h = hc * 112 + hh;
        float wv = Wq[(size_t)h * cD + d];
#pragma unroll
        for (int b = 0; b < cB; ++b) vacc[b] = fmaf(ks_l[b][hh], wv, vacc[b]);
    }
#pragma unroll
    for (int b = 0; b < cB; ++b) red[w][b][l] = vacc[b];
    __syncthreads();
    // final: thread t -> (b, d2); sum 8 wave partials
    int b = t >> 6, d2 = t & 63;
    float acc = 0.f;
#pragma unroll
    for (int ww = 0; ww < 8; ++ww) acc += red[ww][b][d2];
    vpart3[((size_t)hc * cB + b) * cD + dc * 64 + d2] = acc;
}

// kredT: v[b][d] = sum_hc vpart3[hc][b][d] (f4, full sectors); block 4: c[b].
__global__ __launch_bounds__(512) void kredT(const float* __restrict__ vpart3,
                                             const float* __restrict__ bq,
                                             const float* __restrict__ ksum,
                                             float* __restrict__ v,
                                             float* __restrict__ cvec) {
    if (blockIdx.x < 4) {
        int fidx = blockIdx.x * 512 + threadIdx.x;   // 0..2047 f4 of v
        int b = fidx >> 8, j = fidx & 255;
        const float4* p = (const float4*)vpart3 + (size_t)b * 256 + j;
        float4 acc = make_float4(0.f, 0.f, 0.f, 0.f);
#pragma unroll
        for (int hc = 0; hc < 16; ++hc) {
            float4 x2 = p[(size_t)hc * cB * 256];
            acc.x += x2.x; acc.y += x2.y; acc.z += x2.z; acc.w += x2.w;
        }
        ((float4*)v)[fidx] = acc;
    } else {
        int w = threadIdx.x >> 6, l = threadIdx.x & 63;
        float acc = 0.f;
#pragma unroll
        for (int k = 0; k < 28; ++k) {
            int h = l + 64 * k;
            acc += bq[h] * ksum[(size_t)w * cH + h];
        }
#pragma unroll
        for (int off = 32; off; off >>= 1) acc += __shfl_xor(acc, off);
        if (l == 0) cvec[w] = acc;
    }
}

// ---------------------------------------------------------------------------
// k4 (unchanged): scores[b][n] = (x[b,n]·v[b] + c[b]) * (1/(N*sqrt(H)))
__global__ __launch_bounds__(256) void k4_scores(const float* __restrict__ x,
                                                 const float* __restrict__ v,
                                                 const float* __restrict__ cvec,
                                                 float* __restrict__ out) {
    int row0 = blockIdx.x * 16;
    int b = row0 / cN;
    __shared__ float4 vs[cD / 4];
    int t = threadIdx.x;
    vs[t] = ((const float4*)(v + (size_t)b * cD))[t];
    __syncthreads();
    int w = t >> 6, l = t & 63;
    float4 vv[4];
#pragma unroll
    for (int j = 0; j < 4; ++j) vv[j] = vs[l + 64 * j];
    float cb = cvec[b];
    const float scale = (1.0f / 4096.0f) * (1.0f / sqrtf(1792.0f));
    int row = row0 + w * 4;
#pragma unroll
    for (int rp = 0; rp < 2; ++rp) {
        const float4* xa = (const float4*)(x + (size_t)(row + 2 * rp) * cD);
        const float4* xb = (const float4*)(x + (size_t)(row + 2 * rp + 1) * cD);
        float a0 = 0.f, a1 = 0.f;
#pragma unroll
        for (int j = 0; j < 4; ++j) {
            a0 += dot4(xa[l + 64 * j], vv[j]);
            a1 += dot4(xb[l + 64 * j], vv[j]);
        }
#pragma unroll
        for (int off = 32; off; off >>= 1) {
            a0 += __shfl_xor(a0, off);
            a1 += __shfl_xor(a1, off);
        }
        if (l == 0) {
            out[row + 2 * rp]     = (a0 + cb) * scale;
            out[row + 2 * rp + 1] = (a1 + cb) * scale;
        }
    }
}

// ---------------------------------------------------------------------------
// Fallback kernels (ws too small): float atomics, pre-zeroed accumulators.
__global__ __launch_bounds__(256) void k1_atomic(const float* __restrict__ x,
                                                 float* __restrict__ xsum) {
    int bid = blockIdx.x;
    int b = bid >> 7, ns = bid & 127;
    const float4* xp = (const float4*)(x + ((size_t)b * cN + (size_t)ns * 32) * cD);
    int t = threadIdx.x;
    float4 acc = make_float4(0.f, 0.f, 0.f, 0.f);
    for (int r = 0; r < 32; ++r) {
        float4 v = xp[(size_t)r * (cD / 4) + t];
        acc.x += v.x; acc.y += v.y; acc.z += v.z; acc.w += v.w;
    }
    float* dst = xsum + (size_t)b * cD + t * 4;
    atomicAdd(dst + 0, acc.x);
    atomicAdd(dst + 1, acc.y);
    atomicAdd(dst + 2, acc.z);
    atomicAdd(dst + 3, acc.w);
}

__global__ __launch_bounds__(512) void k23_atomic(const float* __restrict__ xsum,
                                                  const float* __restrict__ Wk,
                                                  const float* __restrict__ bk,
                                                  const float* __restrict__ Wq,
                                                  const float* __restrict__ bq,
                                                  float* __restrict__ v,
                                                  float* __restrict__ cvec) {
    int w = threadIdx.x >> 6, l = threadIdx.x & 63;
    int b = w;
    int h0 = blockIdx.x * 8;
    const float4* xs4 = (const float4*)(xsum + (size_t)b * cD);
    float4 xr[4];
#pragma unroll
    for (int j = 0; j < 4; ++j) xr[j] = xs4[l + 64 * j];
    float4 vacc[4];
#pragma unroll
    for (int j = 0; j < 4; ++j) vacc[j] = make_float4(0.f, 0.f, 0.f, 0.f);
    float cacc = 0.f;
    for (int i = 0; i < 8; ++i) {
        int h = h0 + i;
        const float4* wk4 = (const float4*)(Wk + (size_t)h * cD);
        float pd = 0.f;
#pragma unroll
        for (int j = 0; j < 4; ++j) pd += dot4(wk4[l + 64 * j], xr[j]);
#pragma unroll
        for (int off = 32; off; off >>= 1) pd += __shfl_xor(pd, off);
        float ks = pd + (float)cN * bk[h];
        cacc += bq[h] * ks;
        const float4* wq4 = (const float4*)(Wq + (size_t)h * cD);
#pragma unroll
        for (int j = 0; j < 4; ++j) {
            float4 q = wq4[l + 64 * j];
            vacc[j].x = fmaf(q.x, ks, vacc[j].x);
            vacc[j].y = fmaf(q.y, ks, vacc[j].y);
            vacc[j].z = fmaf(q.z, ks, vacc[j].z);
            vacc[j].w = fmaf(q.w, ks, vacc[j].w);
        }
    }
    float* vb = v + (size_t)b * cD;
#pragma unroll
    for (int j = 0; j < 4; ++j) {
        int d = 4 * (l + 64 * j);
        atomicAdd(vb + d + 0, vacc[j].x);
        atomicAdd(vb + d + 1, vacc[j].y);
        atomicAdd(vb + d + 2, vacc[j].z);
        atomicAdd(vb + d + 3, vacc[j].w);
    }
    if (l == 0) atomicAdd(&cvec[b], cacc);
}

// ---------------------------------------------------------------------------
extern "C" void kernel_launch(void* const* d_in, const int* in_sizes, int n_in,
                              void* d_out, int out_size, void* d_ws, size_t ws_size,
                              hipStream_t stream) {
    const float* x  = (const float*)d_in[0];
    const float* Wq = (const float*)d_in[1];
    const float* bq = (const float*)d_in[2];
    const float* Wk = (const float*)d_in[3];
    const float* bk = (const float*)d_in[4];
    float* out = (float*)d_out;
    float* ws  = (float*)d_ws;

    float* xsum   = ws + OFF_XSUM;
    float* ksum   = ws + OFF_KSUM;
    float* v      = ws + OFF_V;
    float* cvec   = ws + OFF_C;
    float* vpart3 = ws + OFF_VP3;
    float* part2  = ws + OFF_PART2;
    float* part   = ws + OFF_PART;

    const bool det = ws_size >= TOTAL_DET_FLOATS * sizeof(float);

    if (det) {
        k1a_partial<<<1024, 256, 0, stream>>>(x, part);        // x pass 1 (HBM, ~20us)
        k1bA<<<128, 256, 0, stream>>>(part, part2);            // contiguous slab reduce
        k1bB<<<4, 512, 0, stream>>>(part2, xsum);              // f4 tail reduce
        KS<<<cH / 8, 512, 0, stream>>>(xsum, Wk, bk, ksum);    // Wk once, 7.3MB
        KV<<<256, 512, 0, stream>>>(ksum, Wq, vpart3);         // Wq once, disjoint tiles
        kredT<<<5, 512, 0, stream>>>(vpart3, bq, ksum, v, cvec); // f4 tail + c
    } else {
        hipMemsetAsync(d_ws, 0, SMALL_FLOATS * sizeof(float), stream);
        k1_atomic<<<1024, 256, 0, stream>>>(x, xsum);
        k23_atomic<<<cH / 8, 512, 0, stream>>>(xsum, Wk, bk, Wq, bq, v, cvec);
    }

    k4_scores<<<(cB * cN) / 16, 256, 0, stream>>>(x, v, cvec, out); // x pass 2 (L3)
}